// Round 1
// baseline (217.165 us; speedup 1.0000x reference)
//
#include <hip/hip_runtime.h>
#include <float.h>

#define FH 64
#define FW 64
#define FC 256
#define NB 4
#define NR 128
#define NREG 32
#define POOLH 3
#define POOLW 3
#define IOU_THR 0.4f

// pooled output elements: B * 32 * 3 * 3 * C
#define POOLED_ELEMS (NB * NREG * POOLH * POOLW * FC)

// Python floor-division semantics for /2 on possibly-negative ints:
// arithmetic shift right == floor division by 2 on two's complement.
__device__ inline void fix_axis(int mn, int mx, int ps, int fs, int& omin, int& omax) {
    int pad = ps - (mx - mn);
    bool fix_min = mn < (pad >> 1);
    bool fix_max = (fs - mx) < ((1 + pad) >> 1);
    bool sym = (pad > 0) && !(fix_min || fix_max);
    omin = sym ? (mn - (pad >> 1)) : mn;
    omax = sym ? (mx + ((1 + pad) >> 1)) : mx;
    if ((pad > 0) && fix_min) { omin = 0; omax = ps; }
    if ((pad > 0) && fix_max) { omin = fs - ps; omax = fs; }  // applied after, matches ref order
}

__global__ __launch_bounds__(256) void roipool_kernel(
    const float* __restrict__ features,  // (B, H, W, C)
    const float* __restrict__ roi,       // (B, R, 4)
    float* __restrict__ out)             // pooled (B,32,3,3,C) ++ roi_clipped (B,32,4)
{
    const int blk = blockIdx.x;
    const int b = blk >> 5;   // batch
    const int r = blk & 31;   // region slot within batch
    const int tid = threadIdx.x;

    __shared__ float sx1[NR], sy1[NR], sx2[NR], sy2[NR], sarea[NR];
    __shared__ int skeep[NR];
    __shared__ int sidx;      // this block's kept box index
    __shared__ int sbox[4];   // clipped x, y, w, h

    // Load boxes for this batch
    if (tid < NR) {
        const float* rp = roi + ((size_t)b * NR + tid) * 4;
        float x = rp[0], y = rp[1], w = rp[2], h = rp[3];
        sx1[tid] = x;
        sy1[tid] = y;
        sx2[tid] = x + w;
        sy2[tid] = y + h;
        sarea[tid] = w * h;
        skeep[tid] = 1;
    }
    __syncthreads();

    // Sequential NMS: iteration p suppresses j>p with IoU>thr if p still kept.
    // Each thread writes only its own skeep slot -> no intra-iteration races;
    // __syncthreads orders iteration p-1 writes before iteration p reads.
    for (int p = 0; p < NR - 1; ++p) {
        int kp = skeep[p];
        if (kp && tid < NR && tid > p && skeep[tid]) {
            float iw = fminf(sx2[p], sx2[tid]) - fmaxf(sx1[p], sx1[tid]);
            iw = fmaxf(iw, 0.0f);
            float ih = fminf(sy2[p], sy2[tid]) - fmaxf(sy1[p], sy1[tid]);
            ih = fmaxf(ih, 0.0f);
            float inter = iw * ih;
            float iou = inter / (sarea[p] + sarea[tid] - inter);
            if (iou > IOU_THR) skeep[tid] = 0;
        }
        __syncthreads();
    }

    // r-th kept index (ascending), padded with R-1 = 127
    if (tid == 0) {
        int cnt = 0;
        int found = NR - 1;
        for (int j = 0; j < NR; ++j) {
            if (skeep[j]) {
                if (cnt == r) { found = j; break; }
                ++cnt;
            }
        }
        sidx = found;
    }
    __syncthreads();

    // Clip the selected box (thread 0), write roi_clipped output as floats
    if (tid == 0) {
        int i = sidx;
        const float* rp = roi + ((size_t)b * NR + i) * 4;
        float x = rp[0], y = rp[1], w = rp[2], h = rp[3];
        int x_min = (int)fmaxf(0.0f, x);
        int y_min = (int)fmaxf(0.0f, y);
        int x_max = (int)fminf((float)FW, x + w);
        int y_max = (int)fminf((float)FH, y + h);
        int xmn, xmx, ymn, ymx;
        fix_axis(x_min, x_max, POOLW, FW, xmn, xmx);
        fix_axis(y_min, y_max, POOLH, FH, ymn, ymx);
        sbox[0] = xmn;
        sbox[1] = ymn;
        sbox[2] = xmx - xmn;
        sbox[3] = ymx - ymn;
        float* orc = out + POOLED_ELEMS + ((size_t)(b * NREG + r)) * 4;
        orc[0] = (float)xmn;
        orc[1] = (float)ymn;
        orc[2] = (float)(xmx - xmn);
        orc[3] = (float)(ymx - ymn);
    }
    __syncthreads();

    // Max-pool: thread owns channel c = tid. Loop cells outer so the running
    // max stays in a scalar register (no dynamic indexing -> no scratch).
    const int x = sbox[0], y = sbox[1], w = sbox[2], h = sbox[3];
    const int hh = h / POOLH;   // h // 3, >= 1 (clip guarantees h >= 3)
    const int ww = w / POOLW;
    const float* fb = features + (size_t)b * FH * FW * FC + tid;
    float* ob = out + ((size_t)(b * NREG + r) * (POOLH * POOLW)) * FC + tid;

    for (int i = 0; i < POOLH; ++i) {
        int r0 = y + i * hh;
        int r1 = (i < POOLH - 1) ? (y + (i + 1) * hh) : (y + h);
        for (int j = 0; j < POOLW; ++j) {
            int c0 = x + j * ww;
            int c1 = (j < POOLW - 1) ? (x + (j + 1) * ww) : (x + w);
            float m = -FLT_MAX;  // matches jnp.finfo(f32).min
            for (int rr = r0; rr < r1; ++rr) {
                const float* rowp = fb + (size_t)(rr * FW) * FC;
                for (int cc = c0; cc < c1; ++cc) {
                    m = fmaxf(m, rowp[(size_t)cc * FC]);
                }
            }
            ob[(i * POOLW + j) * FC] = m;
        }
    }
}

extern "C" void kernel_launch(void* const* d_in, const int* in_sizes, int n_in,
                              void* d_out, int out_size, void* d_ws, size_t ws_size,
                              hipStream_t stream) {
    const float* features = (const float*)d_in[0];  // (4, 64, 64, 256) f32
    const float* roi = (const float*)d_in[1];       // (4, 128, 4) f32
    float* out = (float*)d_out;                     // 294912 + 512 f32 elems
    (void)in_sizes; (void)n_in; (void)out_size; (void)d_ws; (void)ws_size;

    roipool_kernel<<<NB * NREG, 256, 0, stream>>>(features, roi, out);
}

// Round 2
// 107.493 us; speedup vs baseline: 2.0203x; 2.0203x over previous
//
#include <hip/hip_runtime.h>
#include <float.h>

#define FH 64
#define FW 64
#define FC 256
#define NB 4
#define NR 128
#define NREG 32
#define POOLH 3
#define POOLW 3
#define IOU_THR 0.4f

#define POOLED_ELEMS (NB * NREG * POOLH * POOLW * FC)

// Python floor-division semantics for /2 on possibly-negative ints:
// arithmetic shift right == floor division by 2 on two's complement.
__device__ inline void fix_axis(int mn, int mx, int ps, int fs, int& omin, int& omax) {
    int pad = ps - (mx - mn);
    bool fix_min = mn < (pad >> 1);
    bool fix_max = (fs - mx) < ((1 + pad) >> 1);
    bool sym = (pad > 0) && !(fix_min || fix_max);
    omin = sym ? (mn - (pad >> 1)) : mn;
    omax = sym ? (mx + ((1 + pad) >> 1)) : mx;
    if ((pad > 0) && fix_min) { omin = 0; omax = ps; }
    if ((pad > 0) && fix_max) { omin = fs - ps; omax = fs; }
}

// K1: one block per batch. Bitmask NMS + clip. Writes roi_clipped (to out)
// and integer boxes (to ws).
__global__ __launch_bounds__(128) void nms_kernel(
    const float* __restrict__ roi,   // (B, R, 4)
    float* __restrict__ out,         // roi_clipped goes at out + POOLED_ELEMS
    int* __restrict__ wsbox)         // (B, 32, 4) ints
{
    const int b = blockIdx.x;
    const int tid = threadIdx.x;     // = box index p, 0..127

    __shared__ float sx1[NR], sy1[NR], sx2[NR], sy2[NR], sarea[NR];
    __shared__ unsigned long long maskLo[NR], maskHi[NR];
    __shared__ unsigned long long skeep[2];
    __shared__ int sidx[NREG];

    {
        const float* rp = roi + ((size_t)b * NR + tid) * 4;
        float x = rp[0], y = rp[1], w = rp[2], h = rp[3];
        sx1[tid] = x; sy1[tid] = y; sx2[tid] = x + w; sy2[tid] = y + h;
        sarea[tid] = w * h;
    }
    if (tid < NREG) sidx[tid] = NR - 1;   // pad with 127
    __syncthreads();

    // Thread p builds its suppression row: bit j set iff j>p && iou(p,j)>thr.
    {
        const int p = tid;
        const float px1 = sx1[p], py1 = sy1[p], px2 = sx2[p], py2 = sy2[p], pa = sarea[p];
        unsigned long long m0 = 0ull, m1 = 0ull;
        #pragma unroll 4
        for (int j = 0; j < NR; ++j) {
            float iw = fmaxf(fminf(px2, sx2[j]) - fmaxf(px1, sx1[j]), 0.0f);
            float ih = fmaxf(fminf(py2, sy2[j]) - fmaxf(py1, sy1[j]), 0.0f);
            float inter = iw * ih;
            float iou = inter / (pa + sarea[j] - inter);
            bool sup = (j > p) && (iou > IOU_THR);
            if (sup) { if (j < 64) m0 |= 1ull << j; else m1 |= 1ull << (j - 64); }
        }
        maskLo[p] = m0; maskHi[p] = m1;
    }
    __syncthreads();

    // Serial resolve (pure reg/LDS bit ops; rows exclude j<=p so no self-kill).
    if (tid == 0) {
        unsigned long long k0 = ~0ull, k1 = ~0ull;
        for (int p = 0; p < NR - 1; ++p) {
            bool kept = (p < 64) ? ((k0 >> p) & 1ull) : ((k1 >> (p - 64)) & 1ull);
            if (kept) { k0 &= ~maskLo[p]; k1 &= ~maskHi[p]; }
        }
        skeep[0] = k0; skeep[1] = k1;
    }
    __syncthreads();

    // Rank-extract: kept j with rank<32 -> sidx[rank]=j (ranks unique, no race).
    {
        const int j = tid;
        unsigned long long k0 = skeep[0], k1 = skeep[1];
        bool kept = (j < 64) ? ((k0 >> j) & 1ull) : ((k1 >> (j - 64)) & 1ull);
        if (kept) {
            int rank;
            if (j < 64) {
                rank = __popcll(k0 & ((j == 0) ? 0ull : ((1ull << j) - 1ull)));
            } else {
                rank = __popcll(k0) +
                       __popcll(k1 & ((j == 64) ? 0ull : ((1ull << (j - 64)) - 1ull)));
            }
            if (rank < NREG) sidx[rank] = j;
        }
    }
    __syncthreads();

    // 32 threads clip their region's box, write outputs.
    if (tid < NREG) {
        const int i = sidx[tid];
        const float* rp = roi + ((size_t)b * NR + i) * 4;
        float x = rp[0], y = rp[1], w = rp[2], h = rp[3];
        int x_min = (int)fmaxf(0.0f, x);
        int y_min = (int)fmaxf(0.0f, y);
        int x_max = (int)fminf((float)FW, x + w);
        int y_max = (int)fminf((float)FH, y + h);
        int xmn, xmx, ymn, ymx;
        fix_axis(x_min, x_max, POOLW, FW, xmn, xmx);
        fix_axis(y_min, y_max, POOLH, FH, ymn, ymx);
        float* orc = out + POOLED_ELEMS + ((size_t)(b * NREG + tid)) * 4;
        orc[0] = (float)xmn;
        orc[1] = (float)ymn;
        orc[2] = (float)(xmx - xmn);
        orc[3] = (float)(ymx - ymn);
        int* wb = wsbox + ((size_t)(b * NREG + tid)) * 4;
        wb[0] = xmn; wb[1] = ymn; wb[2] = xmx - xmn; wb[3] = ymx - ymn;
    }
}

// K2: one block per (region, pool-cell); thread = channel. Coalesced channel
// loads; running max in a scalar register.
__global__ __launch_bounds__(256) void pool_kernel(
    const float* __restrict__ features,  // (B, H, W, C)
    const int* __restrict__ wsbox,       // (B, 32, 4)
    float* __restrict__ out)             // pooled (B,32,3,3,C)
{
    const int blk = blockIdx.x;
    const int reg = blk / (POOLH * POOLW);      // b*32 + r
    const int cell = blk % (POOLH * POOLW);
    const int ci = cell / POOLW, cj = cell % POOLW;
    const int b = reg >> 5;
    const int tid = threadIdx.x;                // channel

    const int* wb = wsbox + (size_t)reg * 4;
    const int x = wb[0], y = wb[1], w = wb[2], h = wb[3];
    const int hh = h / POOLH;
    const int ww = w / POOLW;

    const int r0 = y + ci * hh;
    const int r1 = (ci < POOLH - 1) ? (y + (ci + 1) * hh) : (y + h);
    const int c0 = x + cj * ww;
    const int c1 = (cj < POOLW - 1) ? (x + (cj + 1) * ww) : (x + w);

    const float* fb = features + (size_t)b * FH * FW * FC + tid;
    float m = -FLT_MAX;  // matches jnp.finfo(f32).min
    for (int rr = r0; rr < r1; ++rr) {
        const float* rowp = fb + (size_t)(rr * FW) * FC;
        for (int cc = c0; cc < c1; ++cc) {
            m = fmaxf(m, rowp[(size_t)cc * FC]);
        }
    }
    out[((size_t)reg * (POOLH * POOLW) + cell) * FC + tid] = m;
}

extern "C" void kernel_launch(void* const* d_in, const int* in_sizes, int n_in,
                              void* d_out, int out_size, void* d_ws, size_t ws_size,
                              hipStream_t stream) {
    const float* features = (const float*)d_in[0];  // (4, 64, 64, 256) f32
    const float* roi = (const float*)d_in[1];       // (4, 128, 4) f32
    float* out = (float*)d_out;
    int* wsbox = (int*)d_ws;                        // 512 ints
    (void)in_sizes; (void)n_in; (void)out_size; (void)ws_size;

    nms_kernel<<<NB, NR, 0, stream>>>(roi, out, wsbox);
    pool_kernel<<<NB * NREG * POOLH * POOLW, 256, 0, stream>>>(features, wsbox, out);
}

// Round 3
// 101.953 us; speedup vs baseline: 2.1301x; 1.0543x over previous
//
#include <hip/hip_runtime.h>
#include <float.h>

#define FH 64
#define FW 64
#define FC 256
#define NB 4
#define NR 128
#define NREG 32
#define POOLH 3
#define POOLW 3
#define IOU_THR 0.4f
#define NCELL (POOLH * POOLW)

#define POOLED_ELEMS (NB * NREG * NCELL * FC)

// Python floor-division semantics for /2 on possibly-negative ints:
// arithmetic shift right == floor division by 2 on two's complement.
__device__ inline void fix_axis(int mn, int mx, int ps, int fs, int& omin, int& omax) {
    int pad = ps - (mx - mn);
    bool fix_min = mn < (pad >> 1);
    bool fix_max = (fs - mx) < ((1 + pad) >> 1);
    bool sym = (pad > 0) && !(fix_min || fix_max);
    omin = sym ? (mn - (pad >> 1)) : mn;
    omax = sym ? (mx + ((1 + pad) >> 1)) : mx;
    if ((pad > 0) && fix_min) { omin = 0; omax = ps; }
    if ((pad > 0) && fix_max) { omin = fs - ps; omax = fs; }
}

// r-th set bit of 64-bit mask (r < popcount guaranteed by caller)
__device__ inline int nth_set_bit(unsigned long long m, int r) {
    for (int i = 0; i < r; ++i) m &= (m - 1);   // clear r lowest set bits
    return __ffsll((long long)m) - 1;
}

// One block per (region, pool-cell). Each block redundantly resolves its
// batch's NMS via bitmasks (cheap: ~8 VALU/IoU, division-free), selects the
// r-th kept box, clips, then pools its cell (thread = channel).
__global__ __launch_bounds__(256) void fused_kernel(
    const float* __restrict__ features,  // (B, H, W, C)
    const float* __restrict__ roi,       // (B, R, 4)
    float* __restrict__ out)             // pooled (B,32,3,3,C) ++ roi_clipped (B,32,4)
{
    const int blk = blockIdx.x;
    const int reg = blk / NCELL;              // b*32 + r
    const int cell = blk - reg * NCELL;
    const int ci = cell / POOLW, cj = cell - ci * POOLW;
    const int b = reg >> 5;
    const int r = reg & 31;
    const int tid = threadIdx.x;

    __shared__ float sx1[NR], sy1[NR], sx2[NR], sy2[NR], sarea[NR];
    __shared__ unsigned long long smask[NR][2];
    __shared__ int sbox[4];

    // Load this batch's boxes (vectorized float4 per box)
    if (tid < NR) {
        const float4 bx = *(const float4*)(roi + ((size_t)b * NR + tid) * 4);
        sx1[tid] = bx.x; sy1[tid] = bx.y;
        sx2[tid] = bx.x + bx.z; sy2[tid] = bx.y + bx.w;
        sarea[tid] = bx.z * bx.w;
    }
    __syncthreads();

    // Row-build with all 256 threads: p = tid&127 owns row p; half = tid>>7
    // covers j in [half*64, half*64+64). Division-free IoU test:
    // inter/(A+B-inter) > t  <=>  inter > t*(A+B-inter)   (denom > 0 always).
    {
        const int p = tid & 127;
        const int half = tid >> 7;
        const int j0 = half << 6;
        const float px1 = sx1[p], py1 = sy1[p], px2 = sx2[p], py2 = sy2[p], pa = sarea[p];
        unsigned long long m = 0ull;
        #pragma unroll 8
        for (int t = 0; t < 64; ++t) {
            const int j = j0 + t;
            float iw = fmaxf(fminf(px2, sx2[j]) - fmaxf(px1, sx1[j]), 0.0f);
            float ih = fmaxf(fminf(py2, sy2[j]) - fmaxf(py1, sy1[j]), 0.0f);
            float inter = iw * ih;
            bool sup = (j > p) && (inter > IOU_THR * (pa + sarea[j] - inter));
            m |= ((unsigned long long)sup) << t;
        }
        smask[p][half] = m;
    }
    __syncthreads();

    // Thread 0: serial NMS resolve (bit ops, LDS mask prefetch), select the
    // r-th kept index, clip, publish box; cell==0 also writes roi_clipped.
    if (tid == 0) {
        unsigned long long k0 = ~0ull, k1 = ~0ull;
        unsigned long long n0 = smask[0][0], n1 = smask[0][1];
        for (int p = 0; p < NR - 1; ++p) {
            unsigned long long m0 = n0, m1 = n1;
            n0 = smask[p + 1][0]; n1 = smask[p + 1][1];  // prefetch next row
            bool kept = (p < 64) ? ((k0 >> p) & 1ull) : ((k1 >> (p - 64)) & 1ull);
            if (kept) { k0 &= ~m0; k1 &= ~m1; }
        }
        // r-th kept index (ascending), pad with 127
        int idx = NR - 1;
        int c0 = __popcll(k0);
        if (r < c0) {
            idx = nth_set_bit(k0, r);
        } else {
            int rr = r - c0;
            if (rr < __popcll(k1)) idx = 64 + nth_set_bit(k1, rr);
        }
        // Clip
        const float* rp = roi + ((size_t)b * NR + idx) * 4;
        float x = rp[0], y = rp[1], w = rp[2], h = rp[3];
        int x_min = (int)fmaxf(0.0f, x);
        int y_min = (int)fmaxf(0.0f, y);
        int x_max = (int)fminf((float)FW, x + w);
        int y_max = (int)fminf((float)FH, y + h);
        int xmn, xmx, ymn, ymx;
        fix_axis(x_min, x_max, POOLW, FW, xmn, xmx);
        fix_axis(y_min, y_max, POOLH, FH, ymn, ymx);
        sbox[0] = xmn; sbox[1] = ymn; sbox[2] = xmx - xmn; sbox[3] = ymx - ymn;
        if (cell == 0) {
            float* orc = out + POOLED_ELEMS + ((size_t)reg) * 4;
            orc[0] = (float)xmn;
            orc[1] = (float)ymn;
            orc[2] = (float)(xmx - xmn);
            orc[3] = (float)(ymx - ymn);
        }
    }
    __syncthreads();

    // Pool this block's cell: thread = channel, coalesced loads, scalar max.
    const int x = sbox[0], y = sbox[1], w = sbox[2], h = sbox[3];
    const int hh = h / POOLH;
    const int ww = w / POOLW;
    const int r0 = y + ci * hh;
    const int r1 = (ci < POOLH - 1) ? (y + (ci + 1) * hh) : (y + h);
    const int c0 = x + cj * ww;
    const int c1 = (cj < POOLW - 1) ? (x + (cj + 1) * ww) : (x + w);

    const float* fb = features + (size_t)b * FH * FW * FC + tid;
    float m = -FLT_MAX;  // matches jnp.finfo(f32).min
    for (int rr = r0; rr < r1; ++rr) {
        const float* rowp = fb + (size_t)(rr * FW) * FC;
        for (int cc = c0; cc < c1; ++cc) {
            m = fmaxf(m, rowp[(size_t)cc * FC]);
        }
    }
    out[((size_t)reg * NCELL + cell) * FC + tid] = m;
}

extern "C" void kernel_launch(void* const* d_in, const int* in_sizes, int n_in,
                              void* d_out, int out_size, void* d_ws, size_t ws_size,
                              hipStream_t stream) {
    const float* features = (const float*)d_in[0];  // (4, 64, 64, 256) f32
    const float* roi = (const float*)d_in[1];       // (4, 128, 4) f32
    float* out = (float*)d_out;                     // 294912 + 512 f32 elems
    (void)in_sizes; (void)n_in; (void)out_size; (void)d_ws; (void)ws_size;

    fused_kernel<<<NB * NREG * NCELL, 256, 0, stream>>>(features, roi, out);
}

// Round 4
// 88.026 us; speedup vs baseline: 2.4671x; 1.1582x over previous
//
#include <hip/hip_runtime.h>
#include <float.h>

#define FH 64
#define FW 64
#define FC 256
#define NB 4
#define NR 128
#define NREG 32
#define POOLH 3
#define POOLW 3
#define IOU_THR 0.4f
#define NCELL (POOLH * POOLW)
#define MAXPIX 160   // max cell pixels: (h<=32 -> last band <=12)^2 = 144, padded

#define POOLED_ELEMS (NB * NREG * NCELL * FC)

// Python floor-division semantics for /2 on possibly-negative ints:
// arithmetic shift right == floor division by 2 on two's complement.
__device__ inline void fix_axis(int mn, int mx, int ps, int fs, int& omin, int& omax) {
    int pad = ps - (mx - mn);
    bool fix_min = mn < (pad >> 1);
    bool fix_max = (fs - mx) < ((1 + pad) >> 1);
    bool sym = (pad > 0) && !(fix_min || fix_max);
    omin = sym ? (mn - (pad >> 1)) : mn;
    omax = sym ? (mx + ((1 + pad) >> 1)) : mx;
    if ((pad > 0) && fix_min) { omin = 0; omax = ps; }
    if ((pad > 0) && fix_max) { omin = fs - ps; omax = fs; }
}

// r-th set bit of 64-bit mask (r < popcount guaranteed by caller)
__device__ inline int nth_set_bit(unsigned long long m, int r) {
    for (int i = 0; i < r; ++i) m &= (m - 1);
    return __ffsll((long long)m) - 1;
}

__device__ inline float4 max4(float4 a, float4 b) {
    float4 o;
    o.x = fmaxf(a.x, b.x); o.y = fmaxf(a.y, b.y);
    o.z = fmaxf(a.z, b.z); o.w = fmaxf(a.w, b.w);
    return o;
}

// One block per (region, pool-cell). Redundant bitmask NMS per block (cheap),
// then pooling with float4 channel loads, 4-way pixel split across the 4
// 64-lane groups, and 4x-unrolled load batches for memory-level parallelism.
__global__ __launch_bounds__(256) void fused_kernel(
    const float* __restrict__ features,  // (B, H, W, C)
    const float* __restrict__ roi,       // (B, R, 4)
    float* __restrict__ out)             // pooled (B,32,3,3,C) ++ roi_clipped (B,32,4)
{
    const int blk = blockIdx.x;
    const int reg = blk / NCELL;              // b*32 + r
    const int cell = blk - reg * NCELL;
    const int ci = cell / POOLW, cj = cell - ci * POOLW;
    const int b = reg >> 5;
    const int r = reg & 31;
    const int tid = threadIdx.x;
    const int group = tid >> 6;               // 0..3
    const int lane = tid & 63;

    __shared__ float sx1[NR], sy1[NR], sx2[NR], sy2[NR], sarea[NR];
    __shared__ unsigned long long smask[NR][2];
    __shared__ int sbox[4];
    __shared__ int spix[MAXPIX];              // pixel offsets (floats), channel-independent
    __shared__ float4 sred[4][64];            // per-group partial maxes

    // Load this batch's boxes
    if (tid < NR) {
        const float4 bx = *(const float4*)(roi + ((size_t)b * NR + tid) * 4);
        sx1[tid] = bx.x; sy1[tid] = bx.y;
        sx2[tid] = bx.x + bx.z; sy2[tid] = bx.y + bx.w;
        sarea[tid] = bx.z * bx.w;
    }
    __syncthreads();

    // Row-build: p = tid&127 owns row p; half = tid>>7 covers 64 j's.
    // Division-free IoU: inter/(A+B-inter) > t <=> inter > t*(A+B-inter).
    {
        const int p = tid & 127;
        const int half = tid >> 7;
        const int j0 = half << 6;
        const float px1 = sx1[p], py1 = sy1[p], px2 = sx2[p], py2 = sy2[p], pa = sarea[p];
        unsigned long long m = 0ull;
        #pragma unroll 8
        for (int t = 0; t < 64; ++t) {
            const int j = j0 + t;
            float iw = fmaxf(fminf(px2, sx2[j]) - fmaxf(px1, sx1[j]), 0.0f);
            float ih = fmaxf(fminf(py2, sy2[j]) - fmaxf(py1, sy1[j]), 0.0f);
            float inter = iw * ih;
            bool sup = (j > p) && (inter > IOU_THR * (pa + sarea[j] - inter));
            m |= ((unsigned long long)sup) << t;
        }
        smask[p][half] = m;
    }
    __syncthreads();

    // Thread 0: serial NMS resolve, select r-th kept, clip, publish box.
    if (tid == 0) {
        unsigned long long k0 = ~0ull, k1 = ~0ull;
        unsigned long long n0 = smask[0][0], n1 = smask[0][1];
        for (int p = 0; p < NR - 1; ++p) {
            unsigned long long m0 = n0, m1 = n1;
            n0 = smask[p + 1][0]; n1 = smask[p + 1][1];
            bool kept = (p < 64) ? ((k0 >> p) & 1ull) : ((k1 >> (p - 64)) & 1ull);
            if (kept) { k0 &= ~m0; k1 &= ~m1; }
        }
        int idx = NR - 1;
        int cnt0 = __popcll(k0);
        if (r < cnt0) {
            idx = nth_set_bit(k0, r);
        } else {
            int rr = r - cnt0;
            if (rr < __popcll(k1)) idx = 64 + nth_set_bit(k1, rr);
        }
        const float* rp = roi + ((size_t)b * NR + idx) * 4;
        float x = rp[0], y = rp[1], w = rp[2], h = rp[3];
        int x_min = (int)fmaxf(0.0f, x);
        int y_min = (int)fmaxf(0.0f, y);
        int x_max = (int)fminf((float)FW, x + w);
        int y_max = (int)fminf((float)FH, y + h);
        int xmn, xmx, ymn, ymx;
        fix_axis(x_min, x_max, POOLW, FW, xmn, xmx);
        fix_axis(y_min, y_max, POOLH, FH, ymn, ymx);
        sbox[0] = xmn; sbox[1] = ymn; sbox[2] = xmx - xmn; sbox[3] = ymx - ymn;
        if (cell == 0) {
            float* orc = out + POOLED_ELEMS + ((size_t)reg) * 4;
            orc[0] = (float)xmn;
            orc[1] = (float)ymn;
            orc[2] = (float)(xmx - xmn);
            orc[3] = (float)(ymx - ymn);
        }
    }
    __syncthreads();

    // Cell bounds (all threads)
    const int x = sbox[0], y = sbox[1], w = sbox[2], h = sbox[3];
    const int hh = h / POOLH;
    const int ww = w / POOLW;
    const int r0 = y + ci * hh;
    const int r1 = (ci < POOLH - 1) ? (y + (ci + 1) * hh) : (y + h);
    const int c0 = x + cj * ww;
    const int c1 = (cj < POOLW - 1) ? (x + (cj + 1) * ww) : (x + w);
    const int ncols = c1 - c0;
    const int n = (r1 - r0) * ncols;          // 1..144

    // Precompute pixel offsets (channel-independent): spix[k] for k < n.
    if (tid < n) {
        int q = tid / ncols;
        int cc = tid - q * ncols;
        spix[tid] = ((r0 + q) * FW + (c0 + cc)) * FC;
    }
    __syncthreads();

    // Pooling: lane owns channels [4*lane, 4*lane+4) (float4). Group g takes
    // pixels k = g, g+4, g+8, ...; batches of 4 keep 4 loads in flight.
    const float* fbase = features + (size_t)b * FH * FW * FC;
    const float4 negv = {-FLT_MAX, -FLT_MAX, -FLT_MAX, -FLT_MAX};
    float4 m0 = negv, m1 = negv, m2 = negv, m3 = negv;
    int k = group;
    for (; k + 12 < n; k += 16) {
        int o0 = spix[k], o1 = spix[k + 4], o2 = spix[k + 8], o3 = spix[k + 12];
        float4 v0 = ((const float4*)(fbase + o0))[lane];
        float4 v1 = ((const float4*)(fbase + o1))[lane];
        float4 v2 = ((const float4*)(fbase + o2))[lane];
        float4 v3 = ((const float4*)(fbase + o3))[lane];
        m0 = max4(m0, v0); m1 = max4(m1, v1);
        m2 = max4(m2, v2); m3 = max4(m3, v3);
    }
    for (; k < n; k += 4) {
        float4 v = ((const float4*)(fbase + spix[k]))[lane];
        m0 = max4(m0, v);
    }
    sred[group][lane] = max4(max4(m0, m1), max4(m2, m3));
    __syncthreads();

    // Final reduce over the 4 groups; coalesced float4 store.
    if (tid < 64) {
        float4 a = max4(max4(sred[0][tid], sred[1][tid]),
                        max4(sred[2][tid], sred[3][tid]));
        float4* ob = (float4*)(out + ((size_t)reg * NCELL + cell) * FC);
        ob[tid] = a;
    }
}

extern "C" void kernel_launch(void* const* d_in, const int* in_sizes, int n_in,
                              void* d_out, int out_size, void* d_ws, size_t ws_size,
                              hipStream_t stream) {
    const float* features = (const float*)d_in[0];  // (4, 64, 64, 256) f32
    const float* roi = (const float*)d_in[1];       // (4, 128, 4) f32
    float* out = (float*)d_out;                     // 294912 + 512 f32 elems
    (void)in_sizes; (void)n_in; (void)out_size; (void)d_ws; (void)ws_size;

    fused_kernel<<<NB * NREG * NCELL, 256, 0, stream>>>(features, roi, out);
}

// Round 5
// 80.235 us; speedup vs baseline: 2.7066x; 1.0971x over previous
//
#include <hip/hip_runtime.h>
#include <float.h>

#define FH 64
#define FW 64
#define FC 256
#define NB 4
#define NR 128
#define NREG 32
#define POOLH 3
#define POOLW 3
#define IOU_THR 0.4f
#define NCELL (POOLH * POOLW)
#define MAXPIX 160   // max cell pixels: last band <= 12 -> 12*12=144, padded

#define POOLED_ELEMS (NB * NREG * NCELL * FC)

// Python floor-division semantics for /2 on possibly-negative ints:
// arithmetic shift right == floor division by 2 on two's complement.
__device__ inline void fix_axis(int mn, int mx, int ps, int fs, int& omin, int& omax) {
    int pad = ps - (mx - mn);
    bool fix_min = mn < (pad >> 1);
    bool fix_max = (fs - mx) < ((1 + pad) >> 1);
    bool sym = (pad > 0) && !(fix_min || fix_max);
    omin = sym ? (mn - (pad >> 1)) : mn;
    omax = sym ? (mx + ((1 + pad) >> 1)) : mx;
    if ((pad > 0) && fix_min) { omin = 0; omax = ps; }
    if ((pad > 0) && fix_max) { omin = fs - ps; omax = fs; }
}

__device__ inline float4 max4(float4 a, float4 b) {
    float4 o;
    o.x = fmaxf(a.x, b.x); o.y = fmaxf(a.y, b.y);
    o.z = fmaxf(a.z, b.z); o.w = fmaxf(a.w, b.w);
    return o;
}

// Broadcast lane `lane`'s 64-bit value to all lanes of the wave (lane uniform).
__device__ inline unsigned long long readlane64(unsigned long long v, int lane) {
    unsigned lo = (unsigned)__builtin_amdgcn_readlane((int)(unsigned)v, lane);
    unsigned hi = (unsigned)__builtin_amdgcn_readlane((int)(unsigned)(v >> 32), lane);
    return ((unsigned long long)hi << 32) | lo;
}

// One block per (region, pool-cell). Redundant bitmask NMS per block, resolve
// via kept-bit scan on wave 0 with register-held rows (readlane fetch), then
// float4 pooling with 4-way pixel split + 4 loads in flight.
__global__ __launch_bounds__(256) void fused_kernel(
    const float* __restrict__ features,  // (B, H, W, C)
    const float* __restrict__ roi,       // (B, R, 4)
    float* __restrict__ out)             // pooled (B,32,3,3,C) ++ roi_clipped (B,32,4)
{
    // XCD batch-affinity swizzle: consecutive hw block IDs round-robin the 8
    // XCDs (id & 7). Put batch b's 288 blocks on XCD pair {2b, 2b+1} so its
    // 4 MB feature slab stays resident in 8 MB of paired L2.
    const int hwid = blockIdx.x;
    const int b = (hwid >> 1) & 3;
    const int j = (hwid >> 3) * 2 + (hwid & 1);   // 0..287 within batch
    const int r = j / NCELL;                      // region 0..31
    const int cell = j - r * NCELL;               // 0..8
    const int ci = cell / POOLW, cj = cell - ci * POOLW;
    const int reg = b * NREG + r;
    const int tid = threadIdx.x;
    const int group = tid >> 6;                   // 0..3
    const int lane = tid & 63;

    __shared__ float sx1[NR], sy1[NR], sx2[NR], sy2[NR], sarea[NR];
    __shared__ unsigned long long smask[NR][2];
    __shared__ int sbox[4];
    __shared__ int spix[MAXPIX];
    __shared__ float4 sred[4][64];

    // Load this batch's boxes
    if (tid < NR) {
        const float4 bx = *(const float4*)(roi + ((size_t)b * NR + tid) * 4);
        sx1[tid] = bx.x; sy1[tid] = bx.y;
        sx2[tid] = bx.x + bx.z; sy2[tid] = bx.y + bx.w;
        sarea[tid] = bx.z * bx.w;
    }
    __syncthreads();

    // Row-build: p = tid&127 owns row p; half = tid>>7 covers 64 j's.
    // Division-free IoU: inter/(A+B-inter) > t <=> inter > t*(A+B-inter).
    {
        const int p = tid & 127;
        const int half = tid >> 7;
        const int j0 = half << 6;
        const float px1 = sx1[p], py1 = sy1[p], px2 = sx2[p], py2 = sy2[p], pa = sarea[p];
        unsigned long long m = 0ull;
        #pragma unroll 8
        for (int t = 0; t < 64; ++t) {
            const int jj = j0 + t;
            float iw = fmaxf(fminf(px2, sx2[jj]) - fmaxf(px1, sx1[jj]), 0.0f);
            float ih = fmaxf(fminf(py2, sy2[jj]) - fmaxf(py1, sy1[jj]), 0.0f);
            float inter = iw * ih;
            bool sup = (jj > p) && (inter > IOU_THR * (pa + sarea[jj] - inter));
            m |= ((unsigned long long)sup) << t;
        }
        smask[p][half] = m;
    }
    __syncthreads();

    // Resolve on wave 0: scan kept bits (a box still set when reached is
    // final-kept -> enumerate kept in ascending order, stop at 32). Rows are
    // held in wave-0 registers; fetch by readlane (no LDS latency).
    if (tid < 64) {
        const unsigned long long aLo = smask[tid][0];       // row tid, bits [0,64)
        const unsigned long long aHi = smask[tid][1];       // row tid, bits [64,128)
        const unsigned long long bHi = smask[tid + 64][1];  // row tid+64 (low half is 0)

        unsigned long long k1 = ~0ull;   // half-1 survivors under half-0 kept rows
        int cnt = 0, idx = NR - 1;

        unsigned long long cur = ~0ull;  // half-0 candidates
        while (cur && cnt < NREG) {
            int p = __ffsll((unsigned long long)cur) - 1;
            if (cnt == r) idx = p;
            ++cnt;
            int ps = __builtin_amdgcn_readfirstlane(p);
            unsigned long long m0 = readlane64(aLo, ps);
            unsigned long long m1 = readlane64(aHi, ps);
            cur = (cur & (cur - 1)) & ~m0;   // drop p + its suppressions
            k1 &= ~m1;
        }
        cur = k1;
        while (cur && cnt < NREG) {
            int p = __ffsll((unsigned long long)cur) - 1;
            if (cnt == r) idx = 64 + p;
            ++cnt;
            int ps = __builtin_amdgcn_readfirstlane(p);
            unsigned long long m1 = readlane64(bHi, ps);
            cur = (cur & (cur - 1)) & ~m1;
        }

        if (tid == 0) {
            // Clip from LDS: sx2 = x1+w exactly matches reference x+w.
            float x1 = sx1[idx], y1 = sy1[idx], x2f = sx2[idx], y2f = sy2[idx];
            int x_min = (int)fmaxf(0.0f, x1);
            int y_min = (int)fmaxf(0.0f, y1);
            int x_max = (int)fminf((float)FW, x2f);
            int y_max = (int)fminf((float)FH, y2f);
            int xmn, xmx, ymn, ymx;
            fix_axis(x_min, x_max, POOLW, FW, xmn, xmx);
            fix_axis(y_min, y_max, POOLH, FH, ymn, ymx);
            sbox[0] = xmn; sbox[1] = ymn; sbox[2] = xmx - xmn; sbox[3] = ymx - ymn;
            if (cell == 0) {
                float* orc = out + POOLED_ELEMS + ((size_t)reg) * 4;
                orc[0] = (float)xmn;
                orc[1] = (float)ymn;
                orc[2] = (float)(xmx - xmn);
                orc[3] = (float)(ymx - ymn);
            }
        }
    }
    __syncthreads();

    // Cell bounds
    const int x = sbox[0], y = sbox[1], w = sbox[2], h = sbox[3];
    const int hh = h / POOLH;
    const int ww = w / POOLW;
    const int r0 = y + ci * hh;
    const int r1 = (ci < POOLH - 1) ? (y + (ci + 1) * hh) : (y + h);
    const int c0 = x + cj * ww;
    const int c1 = (cj < POOLW - 1) ? (x + (cj + 1) * ww) : (x + w);
    const int ncols = c1 - c0;
    const int n = (r1 - r0) * ncols;          // 1..144

    // Pixel offsets (channel-independent)
    if (tid < n) {
        int q = tid / ncols;
        int cc = tid - q * ncols;
        spix[tid] = ((r0 + q) * FW + (c0 + cc)) * FC;
    }
    __syncthreads();

    // Pooling: lane owns channels [4*lane, 4*lane+4). Group g takes pixels
    // k = g, g+4, ...; batches of 4 loads in flight.
    const float* fbase = features + (size_t)b * FH * FW * FC;
    const float4 negv = {-FLT_MAX, -FLT_MAX, -FLT_MAX, -FLT_MAX};
    float4 m0 = negv, m1 = negv, m2 = negv, m3 = negv;
    int k = group;
    for (; k + 12 < n; k += 16) {
        int o0 = spix[k], o1 = spix[k + 4], o2 = spix[k + 8], o3 = spix[k + 12];
        float4 v0 = ((const float4*)(fbase + o0))[lane];
        float4 v1 = ((const float4*)(fbase + o1))[lane];
        float4 v2 = ((const float4*)(fbase + o2))[lane];
        float4 v3 = ((const float4*)(fbase + o3))[lane];
        m0 = max4(m0, v0); m1 = max4(m1, v1);
        m2 = max4(m2, v2); m3 = max4(m3, v3);
    }
    for (; k < n; k += 4) {
        float4 v = ((const float4*)(fbase + spix[k]))[lane];
        m0 = max4(m0, v);
    }
    sred[group][lane] = max4(max4(m0, m1), max4(m2, m3));
    __syncthreads();

    // Final reduce over the 4 groups; coalesced float4 store.
    if (tid < 64) {
        float4 a = max4(max4(sred[0][tid], sred[1][tid]),
                        max4(sred[2][tid], sred[3][tid]));
        float4* ob = (float4*)(out + ((size_t)reg * NCELL + cell) * FC);
        ob[tid] = a;
    }
}

extern "C" void kernel_launch(void* const* d_in, const int* in_sizes, int n_in,
                              void* d_out, int out_size, void* d_ws, size_t ws_size,
                              hipStream_t stream) {
    const float* features = (const float*)d_in[0];  // (4, 64, 64, 256) f32
    const float* roi = (const float*)d_in[1];       // (4, 128, 4) f32
    float* out = (float*)d_out;                     // 294912 + 512 f32 elems
    (void)in_sizes; (void)n_in; (void)out_size; (void)d_ws; (void)ws_size;

    fused_kernel<<<NB * NREG * NCELL, 256, 0, stream>>>(features, roi, out);
}